// Round 9
// baseline (592.995 us; speedup 1.0000x reference)
//
#include <hip/hip_runtime.h>
#include <math.h>

// Problem constants
#define B_  16
#define F_  8
#define C_  8
#define G_  32
#define G3_ 32768
#define P_  4
#define N_  (B_*F_*C_*G3_)
#define SF_ (C_*G3_)
#define SB_ (F_*SF_)
#define APACK_SZ (P_*F_*9*64*8)

typedef __attribute__((ext_vector_type(8))) short short8v;
typedef __attribute__((ext_vector_type(4))) float f32x4;
typedef unsigned short u16;
typedef unsigned int u32;

__device__ __constant__ int c_k[8][8] = {
  {0,1,2,3,4,5,6,7},
  {1,0,4,5,2,3,7,6},
  {2,4,0,6,1,7,3,5},
  {3,5,6,0,7,1,2,4},
  {4,2,1,7,0,6,5,3},
  {5,3,7,1,6,0,4,2},
  {6,7,3,2,5,4,0,1},
  {7,6,5,4,3,2,1,0}};
__device__ __constant__ float c_s[8][8] = {
  { 1, 1, 1, 1,-1,-1,-1,-1},
  { 1, 1, 1, 1,-1,-1,-1,-1},
  { 1,-1, 1, 1, 1, 1,-1, 1},
  { 1,-1,-1, 1,-1, 1, 1,-1},
  { 1,-1, 1, 1, 1, 1,-1, 1},
  { 1,-1,-1, 1,-1, 1, 1,-1},
  { 1, 1,-1, 1, 1,-1, 1, 1},
  { 1, 1,-1, 1, 1,-1, 1, 1}};

__device__ __forceinline__ float fast_tanh(float v) {
  float e = __expf(2.f * v);
  return 1.f - 2.f / (e + 1.f);
}
__device__ __forceinline__ float fast_sig(float v) {
  return 1.f / (1.f + __expf(-v));
}
__device__ __forceinline__ u32 bf16_rne(float v) {
  u32 u = __float_as_uint(v);
  return (u + 0x7FFFu + ((u >> 16) & 1u)) >> 16;
}
__device__ __forceinline__ u32 pk_bf16(float a, float b) {
  u32 d;
  asm("v_cvt_pk_bf16_f32 %0, %1, %2" : "=v"(d) : "v"(a), "v"(b));
  return d;
}
__device__ __forceinline__ float bl(u32 u) { return __uint_as_float(u << 16); }
__device__ __forceinline__ float bh(u32 u) { return __uint_as_float(u & 0xffff0000u); }

// position swizzle: quad qq of point pt stored at (qq ^ HS(pt)); HS(pt+16)==HS(pt)
#define HS(pt) (((pt) + ((pt) >> 2)) & 3)

// ---------------------------------------------------------------------------
// prep: A fragments.  k-relabel to match point-major B staging:
// hardware (g,e) of the fragment holds logical (zl=g, j=e).
// A[m=(zoff*8+i), (g,e)] = W_eff[i][j=e][dz=g-zoff][t], 0 outside dz in [0,2].
__global__ void prep_kernel(const float* __restrict__ all_weights,
                            const float* __restrict__ mix_logits,
                            u16* __restrict__ Apack,
                            float* __restrict__ mix) {
  int idx = blockIdx.x * 256 + threadIdx.x;
  if (idx < APACK_SZ) {
    int j = idx & 7;            // element e = logical comp j
    int l = (idx >> 3) & 63;
    int rest = idx >> 9;
    int t = rest % 9;
    int fp = rest / 9;
    int f = fp & 7, p = fp >> 3;
    int g = l >> 4, m = l & 15;
    int zoff = m >> 3, i = m & 7;
    int dz = g - zoff;          // logical zl = g
    float val = 0.f;
    if (dz >= 0 && dz <= 2)
      val = c_s[i][j] * all_weights[((f*P_ + p)*27 + (dz*9 + t))*8 + c_k[i][j]];
    Apack[idx] = (u16)bf16_rne(val);
  }
  if (blockIdx.x == 0 && threadIdx.x < P_*F_) {
    int p = threadIdx.x / F_, g = threadIdx.x % F_;
    const float* row = &mix_logits[(p*F_ + g)*F_];
    float mx = row[0];
    for (int f = 1; f < F_; ++f) mx = fmaxf(mx, row[f]);
    float e[F_]; float sum = 0.f;
    for (int f = 0; f < F_; ++f) { e[f] = __expf(row[f] - mx); sum += e[f]; }
    float inv = 1.f / sum;
    for (int f = 0; f < F_; ++f) mix[(p*F_ + g)*F_ + f] = e[f] * inv;
  }
}

// ---------------------------------------------------------------------------
// Fused conv+tanh+mix(+gate).  Block: (b, z-pair, y-tile of 4), ALL 8 fields.
// Packed X layout: [b][f][z][y][x][8 comps] bf16 (16 B per point).
// LDS: 204 points x 16 dwords; quad zl (j0..j7 of plane zl) at pos zl^HS(pt).
// MODE 0: f32 standard in, packed out; 1: packed->packed; 2: packed in,
// gate with f32 state, f32 standard out.
#define TPTS 204     // 6*34

template<int MODE>
__device__ __forceinline__ uint4 field_step(
    int f, const void* __restrict__ xsrc_, const u16* __restrict__ Apack,
    const float* __restrict__ biases, int p, int b, int z0, int y0,
    u32* xk, int tid, int lane, int wid, int g, int ln) {
  if (f) __syncthreads();       // prev field's LDS reads done before overwrite

  // ---- stage field f ----
  if (MODE != 0) {
    // packed input: one uint4 per (plane, point); 768 points, 3 per thread
    const uint4* xp = (const uint4*)xsrc_ + (size_t)(b*8 + f)*G3_;
    #pragma unroll
    for (int it0 = 0; it0 < 3; ++it0) {
      int it = it0*256 + tid;
      int gx = it & 31;
      int pr = it >> 5;              // 0..23
      int zl = pr / 6;
      int row = pr - zl*6;
      int gz = z0 - 2 + zl;
      int gy = y0 - 2 + row;
      uint4 v = {0u,0u,0u,0u};
      if (gz >= 0 && gy >= 0)
        v = xp[gz*1024 + gy*32 + gx];
      int pt = row*34 + 2 + gx;
      *(uint4*)&xk[pt*16 + ((zl ^ HS(pt)) << 2)] = v;
    }
  } else if (tid < 192) {
    // f32 standard input: 4 planes x 6 rows x 8 chunks of 4 x-points
    int zl  = tid / 48;
    int r2  = tid - zl*48;
    int row = r2 >> 3;
    int c   = r2 & 7;
    int gz = z0 - 2 + zl;
    int gy = y0 - 2 + row;
    int gx = c * 4;
    const float* s0 = (const float*)xsrc_ + (size_t)b*SB_ + f*SF_
                    + gz*1024 + gy*32 + gx;
    float4 f0={0,0,0,0},f1={0,0,0,0},f2={0,0,0,0},f3={0,0,0,0};
    float4 f4={0,0,0,0},f5={0,0,0,0},f6={0,0,0,0},f7={0,0,0,0};
    if (gz >= 0 && gy >= 0) {
      f0 = *(const float4*)(s0);
      f1 = *(const float4*)(s0 + G3_);
      f2 = *(const float4*)(s0 + 2*G3_);
      f3 = *(const float4*)(s0 + 3*G3_);
      f4 = *(const float4*)(s0 + 4*G3_);
      f5 = *(const float4*)(s0 + 5*G3_);
      f6 = *(const float4*)(s0 + 6*G3_);
      f7 = *(const float4*)(s0 + 7*G3_);
    }
    int ptb = row*34 + 2 + gx;
    #define STW(px, CC) { \
      uint4 d; d.x = pk_bf16(f0.CC, f1.CC); d.y = pk_bf16(f2.CC, f3.CC); \
      d.z = pk_bf16(f4.CC, f5.CC); d.w = pk_bf16(f6.CC, f7.CC); \
      int pt = ptb + px; \
      *(uint4*)&xk[pt*16 + ((zl ^ HS(pt)) << 2)] = d; }
    STW(0, x) STW(1, y) STW(2, z) STW(3, w)
    #undef STW
  }

  // A fragments for this field (overlaps barrier wait)
  short8v a[9];
  const u16* ap = Apack + (size_t)((p*8 + f) * 9) * 512;
  #pragma unroll
  for (int t = 0; t < 9; ++t)
    a[t] = *(const short8v*)(ap + (t*64 + lane)*8);

  __syncthreads();

  // ---- compute: wave wid owns y row wid, both x halves ----
  f32x4 acc0 = {0.f,0.f,0.f,0.f}, acc1 = {0.f,0.f,0.f,0.f};
  #pragma unroll
  for (int dy = 0; dy < 3; ++dy) {
    int prow = (wid + dy)*34;
    #pragma unroll
    for (int dx = 0; dx < 3; ++dx) {
      int t = dy*3 + dx;
      int pt0 = prow + ln + dx;
      int dwb = pt0*16 + ((g ^ HS(pt0)) << 2);
      short8v b0 = *(const short8v*)&xk[dwb];
      short8v b1 = *(const short8v*)&xk[dwb + 256];   // pt0+16: HS invariant
      acc0 = __builtin_amdgcn_mfma_f32_16x16x32_bf16(a[t], b0, acc0, 0, 0, 0);
      acc1 = __builtin_amdgcn_mfma_f32_16x16x32_bf16(a[t], b1, acc1, 0, 0, 0);
    }
  }

  const float* bb = biases + (f*P_ + p)*8 + (g & 1)*4;
  float b0v = bb[0], b1v = bb[1], b2v = bb[2], b3v = bb[3];
  uint4 yp;
  yp.x = pk_bf16(fast_tanh(acc0[0] + b0v), fast_tanh(acc0[1] + b1v));
  yp.y = pk_bf16(fast_tanh(acc0[2] + b2v), fast_tanh(acc0[3] + b3v));
  yp.z = pk_bf16(fast_tanh(acc1[0] + b0v), fast_tanh(acc1[1] + b1v));
  yp.w = pk_bf16(fast_tanh(acc1[2] + b2v), fast_tanh(acc1[3] + b3v));
  return yp;
}

template<int MODE>
__global__ __launch_bounds__(256, 6)
void fused_kernel(const void* __restrict__ xsrc_,
                  void* __restrict__ xdst_,
                  const float* __restrict__ state,
                  const u16* __restrict__ Apack,
                  const float* __restrict__ biases,
                  const float* __restrict__ mixb,
                  const float* __restrict__ pal,
                  const float* __restrict__ gw,
                  const float* __restrict__ gb,
                  int p) {
  __shared__ __align__(16) u32 xk[TPTS * 16];   // 13056 B

  int bid = blockIdx.x;
  int yt = bid & 7;
  int zt = (bid >> 3) & 15;
  int b  =  bid >> 7;
  int z0 = zt * 2, y0 = yt * 4;
  int tid  = threadIdx.x;
  int lane = tid & 63;
  int wid  = tid >> 6;
  int g    = lane >> 4;
  int ln   = lane & 15;

  // zero x-halo points (x'=0,1): 6 rows x 2 pts x 16 dwords = 192
  if (tid < 192) {
    int pt = (tid >> 5) * 34 + ((tid >> 4) & 1);
    xk[pt*16 + (tid & 15)] = 0u;
  }

  uint4 yp0 = field_step<MODE>(0, xsrc_, Apack, biases, p, b, z0, y0, xk, tid, lane, wid, g, ln);
  uint4 yp1 = field_step<MODE>(1, xsrc_, Apack, biases, p, b, z0, y0, xk, tid, lane, wid, g, ln);
  uint4 yp2 = field_step<MODE>(2, xsrc_, Apack, biases, p, b, z0, y0, xk, tid, lane, wid, g, ln);
  uint4 yp3 = field_step<MODE>(3, xsrc_, Apack, biases, p, b, z0, y0, xk, tid, lane, wid, g, ln);
  uint4 yp4 = field_step<MODE>(4, xsrc_, Apack, biases, p, b, z0, y0, xk, tid, lane, wid, g, ln);
  uint4 yp5 = field_step<MODE>(5, xsrc_, Apack, biases, p, b, z0, y0, xk, tid, lane, wid, g, ln);
  uint4 yp6 = field_step<MODE>(6, xsrc_, Apack, biases, p, b, z0, y0, xk, tid, lane, wid, g, ln);
  uint4 yp7 = field_step<MODE>(7, xsrc_, Apack, biases, p, b, z0, y0, xk, tid, lane, wid, g, ln);

  // ---- epilogue: unpack y, 8x8 mix, residual (+gate) ----
  float yf[8][8];
  #define UNP(F, YPV) \
    yf[F][0]=bl(YPV.x); yf[F][1]=bh(YPV.x); yf[F][2]=bl(YPV.y); yf[F][3]=bh(YPV.y); \
    yf[F][4]=bl(YPV.z); yf[F][5]=bh(YPV.z); yf[F][6]=bl(YPV.w); yf[F][7]=bh(YPV.w);
  UNP(0,yp0) UNP(1,yp1) UNP(2,yp2) UNP(3,yp3)
  UNP(4,yp4) UNP(5,yp5) UNP(6,yp6) UNP(7,yp7)
  #undef UNP

  float alpha = fast_sig(pal[p]);
  float na = 1.f - alpha;
  int zoff = g >> 1;
  int i0 = (g & 1)*4;
  // point index of this thread's xhalf-0 output (in 16B points, per field gg)
  size_t pt0 = (size_t)(b*8)*G3_ + (size_t)(z0 + zoff)*1024
             + (size_t)(y0 + wid)*32 + ln;
  // f32-standard element base (for MODE 0 xb read / MODE 2 state+out)
  size_t ebase = (size_t)b*SB_ + (size_t)(z0 + zoff)*1024
               + (size_t)(y0 + wid)*32 + ln;

  #pragma unroll
  for (int gg = 0; gg < 8; ++gg) {
    const float* mr = mixb + (p*8 + gg)*8;
    float o[8] = {0.f,0.f,0.f,0.f,0.f,0.f,0.f,0.f};
    #pragma unroll
    for (int f = 0; f < 8; ++f) {
      float m = mr[f];
      #pragma unroll
      for (int e = 0; e < 8; ++e) o[e] = fmaf(m, yf[f][e], o[e]);
    }
    size_t ptg = pt0 + (size_t)gg*G3_;        // packed point index, xhalf 0
    size_t og  = ebase + (size_t)gg*SF_;      // f32-standard base

    float xb[8];
    if (MODE == 0) {
      #pragma unroll
      for (int e = 0; e < 8; ++e)
        xb[e] = ((const float*)xsrc_)[og + (size_t)(i0 + (e & 3))*G3_ + (e >> 2)*16];
    } else {
      const uint2* xbp = (const uint2*)xsrc_;
      uint2 u0 = xbp[ptg*2 + (g & 1)];
      uint2 u1 = xbp[(ptg + 16)*2 + (g & 1)];
      xb[0]=bl(u0.x); xb[1]=bh(u0.x); xb[2]=bl(u0.y); xb[3]=bh(u0.y);
      xb[4]=bl(u1.x); xb[5]=bh(u1.x); xb[6]=bl(u1.y); xb[7]=bh(u1.y);
    }

    if (MODE == 2) {
      #pragma unroll
      for (int e = 0; e < 8; ++e) {
        size_t idx = og + (size_t)(i0 + (e & 3))*G3_ + (e >> 2)*16;
        float xf = alpha*xb[e] + na*o[e];
        float st = state[idx];
        float w  = gw[gg*8 + i0 + (e & 3)];
        float bv = gb[gg*8 + i0 + (e & 3)];
        float gt = fast_sig(w*st + bv);
        ((float*)xdst_)[idx] = gt*st + (1.f - gt)*xf;
      }
    } else {
      uint2* xdp = (uint2*)xdst_;
      uint2 w0, w1;
      w0.x = pk_bf16(alpha*xb[0] + na*o[0], alpha*xb[1] + na*o[1]);
      w0.y = pk_bf16(alpha*xb[2] + na*o[2], alpha*xb[3] + na*o[3]);
      w1.x = pk_bf16(alpha*xb[4] + na*o[4], alpha*xb[5] + na*o[5]);
      w1.y = pk_bf16(alpha*xb[6] + na*o[6], alpha*xb[7] + na*o[7]);
      xdp[ptg*2 + (g & 1)]        = w0;
      xdp[(ptg + 16)*2 + (g & 1)] = w1;
    }
  }
}

// ---------------------------------------------------------------------------
extern "C" void kernel_launch(void* const* d_in, const int* in_sizes, int n_in,
                              void* d_out, int out_size, void* d_ws, size_t ws_size,
                              hipStream_t stream) {
  (void)in_sizes; (void)n_in; (void)out_size; (void)ws_size;
  const float* state       = (const float*)d_in[0];
  const float* all_weights = (const float*)d_in[1];
  const float* all_biases  = (const float*)d_in[2];
  const float* mix_logits  = (const float*)d_in[3];
  const float* pal         = (const float*)d_in[4];
  const float* gw          = (const float*)d_in[5];
  const float* gb          = (const float*)d_in[6];
  float* out = (float*)d_out;

  // ws: X0 packed bf16 (N_) | X1 packed bf16 (N_) | Apack | mix
  u16* X0 = (u16*)d_ws;
  u16* X1 = X0 + N_;
  u16* Apack = X1 + N_;
  float* mixb = (float*)(Apack + APACK_SZ);

  prep_kernel<<<dim3(APACK_SZ/256), dim3(256), 0, stream>>>(
      all_weights, mix_logits, Apack, mixb);

  dim3 grid(2048), blk(256);
  // p0: state(f32) -> X0 ; p1: X0 -> X1 ; p2: X1 -> X0 ; p3: X0 (+state) -> out
  fused_kernel<0><<<grid, blk, 0, stream>>>((const void*)state, (void*)X0, state,
      Apack, all_biases, mixb, pal, gw, gb, 0);
  fused_kernel<1><<<grid, blk, 0, stream>>>((const void*)X0, (void*)X1, state,
      Apack, all_biases, mixb, pal, gw, gb, 1);
  fused_kernel<1><<<grid, blk, 0, stream>>>((const void*)X1, (void*)X0, state,
      Apack, all_biases, mixb, pal, gw, gb, 2);
  fused_kernel<2><<<grid, blk, 0, stream>>>((const void*)X0, (void*)out, state,
      Apack, all_biases, mixb, pal, gw, gb, 3);
}